// Round 2
// baseline (3973.994 us; speedup 1.0000x reference)
//
#include <hip/hip_runtime.h>

#define Tn 2048
#define Hn 128

typedef __attribute__((ext_vector_type(8))) short v8s;
typedef __attribute__((ext_vector_type(4))) float v4f;

__device__ __forceinline__ unsigned short f2bf(float f) {
  unsigned u = __builtin_bit_cast(unsigned, f);
  return (unsigned short)((u + 0x7fffu + ((u >> 16) & 1u)) >> 16);
}
__device__ __forceinline__ float sigf(float x) {
  return __builtin_amdgcn_rcpf(1.f + __builtin_amdgcn_exp2f(-1.44269504f * x));
}
__device__ __forceinline__ float tanh_(float x) {
  return 1.f - 2.f * __builtin_amdgcn_rcpf(1.f + __builtin_amdgcn_exp2f(2.88539008f * x));
}

// ---------------- layer 0: feats (norms) fused + recurrence ----------------
__global__ void __launch_bounds__(512) lstm0_k(
    const float* __restrict__ x, const float* __restrict__ Wih0,
    const float* __restrict__ Whh0, const float* __restrict__ bih0,
    const float* __restrict__ bhh0, char* __restrict__ ws, int t0, int CH)
{
  const int tid = threadIdx.x;
  const int w = tid >> 6, l = tid & 63, lr = l & 15, g = l >> 4;
  const int bt = blockIdx.x;
  const int rowb = lr & 7;
  float* hstate = (float*)(ws);
  float* cstate = (float*)(ws + (256 << 10));
  char*  y0c    = ws + (1 << 20);
  __shared__ unsigned hbuf[2][512];     // [8 rows][256B] swizzled bf16 h
  __shared__ unsigned fbuf[2][32][8];   // packed (acc,gyro) bf16 per (t,b)

  // weights -> A fragments (rows = gates, k = hidden)
  v8s A[4][4], Ain[4]; v4f bias[4];
  #pragma unroll
  for (int t = 0; t < 4; t++) {
    const int gate0 = t * 128 + w * 16 + lr;
    #pragma unroll
    for (int kt = 0; kt < 4; kt++) {
      const float* p = Whh0 + gate0 * Hn + kt * 32 + g * 8;
      v8s a;
      #pragma unroll
      for (int i = 0; i < 8; i++) a[i] = (short)f2bf(p[i]);
      A[t][kt] = a;
    }
    v8s ai = {0,0,0,0,0,0,0,0};
    if (g == 0) { ai[0] = (short)f2bf(Wih0[gate0 * 2]); ai[1] = (short)f2bf(Wih0[gate0 * 2 + 1]); }
    Ain[t] = ai;
    const int gb = t * 128 + w * 16 + g * 4;
    v4f bb;
    #pragma unroll
    for (int r = 0; r < 4; r++) bb[r] = bih0[gb + r] + bhh0[gb + r];
    bias[t] = bb;
  }
  unsigned off_k[4];
  #pragma unroll
  for (int kt = 0; kt < 4; kt++)
    off_k[kt] = rowb * 256 + ((((unsigned)kt * 4 + g) ^ (unsigned)rowb) << 4);
  const int dimb = w * 16 + g * 4;
  const unsigned woff = lr * 256 + (((unsigned)dimb * 2) ^ ((unsigned)lr << 4));

  float c4[4], h4[4];
  const int brow = bt * 8 + rowb;
  if (lr < 8) {
    const float4 hv = *(const float4*)(hstate + brow * Hn + dimb);
    const float4 cv = *(const float4*)(cstate + brow * Hn + dimb);
    c4[0] = cv.x; c4[1] = cv.y; c4[2] = cv.z; c4[3] = cv.w;
    uint2 hp;
    hp.x = (unsigned)f2bf(hv.x) | ((unsigned)f2bf(hv.y) << 16);
    hp.y = (unsigned)f2bf(hv.z) | ((unsigned)f2bf(hv.w) << 16);
    *(uint2*)((char*)hbuf[0] + woff) = hp;
  } else { c4[0] = c4[1] = c4[2] = c4[3] = 0.f; }
  h4[0] = h4[1] = h4[2] = h4[3] = 0.f;

  // feats staging: 512 threads -> one vector-norm each per 32-step slot
  const int sb_b = tid >> 6;
  const int sb_t = (tid & 63) >> 1;
  const int sb_c = tid & 1;
  auto stage = [&](int sbase) {
    const float* xp = x + ((size_t)(bt * 8 + sb_b) * Tn + (t0 + sbase + sb_t)) * 6 + sb_c * 3;
    float v0 = xp[0], v1 = xp[1], v2 = xp[2];
    unsigned short nb = f2bf(__builtin_amdgcn_sqrtf(v0 * v0 + v1 * v1 + v2 * v2));
    ((unsigned short*)fbuf[(sbase >> 5) & 1])[(sb_t * 8 + sb_b) * 2 + sb_c] = nb;
  };
  stage(0);
  __syncthreads();

  for (int s = 0; s < CH; ++s) {
    const int p = s & 1;
    if ((s & 31) == 0 && (s + 32) < CH) stage(s + 32);
    uint4 Bf[4];
    const char* hbR = (const char*)hbuf[p];
    #pragma unroll
    for (int kt = 0; kt < 4; kt++) Bf[kt] = *(const uint4*)(hbR + off_k[kt]);
    const unsigned fpk = fbuf[(s >> 5) & 1][s & 31][rowb];
    v8s bin = {0,0,0,0,0,0,0,0};
    if (g == 0) { bin[0] = (short)(fpk & 0xffffu); bin[1] = (short)(fpk >> 16); }
    v4f a0 = bias[0], a1 = bias[1], a2 = bias[2], a3 = bias[3];
    #pragma unroll
    for (int kt = 0; kt < 4; kt++) {
      v8s b = __builtin_bit_cast(v8s, Bf[kt]);
      a0 = __builtin_amdgcn_mfma_f32_16x16x32_bf16(A[0][kt], b, a0, 0, 0, 0);
      a1 = __builtin_amdgcn_mfma_f32_16x16x32_bf16(A[1][kt], b, a1, 0, 0, 0);
      a2 = __builtin_amdgcn_mfma_f32_16x16x32_bf16(A[2][kt], b, a2, 0, 0, 0);
      a3 = __builtin_amdgcn_mfma_f32_16x16x32_bf16(A[3][kt], b, a3, 0, 0, 0);
    }
    a0 = __builtin_amdgcn_mfma_f32_16x16x32_bf16(Ain[0], bin, a0, 0, 0, 0);
    a1 = __builtin_amdgcn_mfma_f32_16x16x32_bf16(Ain[1], bin, a1, 0, 0, 0);
    a2 = __builtin_amdgcn_mfma_f32_16x16x32_bf16(Ain[2], bin, a2, 0, 0, 0);
    a3 = __builtin_amdgcn_mfma_f32_16x16x32_bf16(Ain[3], bin, a3, 0, 0, 0);
    #pragma unroll
    for (int r = 0; r < 4; r++) {
      float cn = sigf(a1[r]) * c4[r] + sigf(a0[r]) * tanh_(a2[r]);
      c4[r] = cn;
      h4[r] = sigf(a3[r]) * tanh_(cn);
    }
    if (lr < 8) {
      uint2 hp;
      hp.x = (unsigned)f2bf(h4[0]) | ((unsigned)f2bf(h4[1]) << 16);
      hp.y = (unsigned)f2bf(h4[2]) | ((unsigned)f2bf(h4[3]) << 16);
      *(uint2*)((char*)hbuf[p ^ 1] + woff) = hp;
      *(uint2*)(y0c + ((size_t)s * 64 + bt) * 2048 + woff) = hp;
    }
    __syncthreads();
  }
  if (lr < 8) {
    *(float4*)(hstate + brow * Hn + dimb) = make_float4(h4[0], h4[1], h4[2], h4[3]);
    *(float4*)(cstate + brow * Hn + dimb) = make_float4(c4[0], c4[1], c4[2], c4[3]);
  }
}

// ---------------- layer 1 ----------------
#define L1_BODY(HBR, HBW, CUR, NXT, SN)                                          \
  {                                                                              \
    _Pragma("unroll")                                                            \
    for (int kt = 0; kt < 4; kt++)                                               \
      NXT[kt] = *(const uint4*)(y0c + (size_t)(SN) * 131072 + tb + off_k[kt]);   \
    uint4 Bf[4];                                                                 \
    _Pragma("unroll")                                                            \
    for (int kt = 0; kt < 4; kt++)                                               \
      Bf[kt] = *(const uint4*)((const char*)(HBR) + off_k[kt]);                  \
    v4f a0 = bias[0], a1 = bias[1], a2 = bias[2], a3 = bias[3];                  \
    _Pragma("unroll")                                                            \
    for (int kt = 0; kt < 4; kt++) {                                             \
      v8s b = __builtin_bit_cast(v8s, Bf[kt]);                                   \
      a0 = __builtin_amdgcn_mfma_f32_16x16x32_bf16(Ah[0][kt], b, a0, 0, 0, 0);   \
      a1 = __builtin_amdgcn_mfma_f32_16x16x32_bf16(Ah[1][kt], b, a1, 0, 0, 0);   \
      a2 = __builtin_amdgcn_mfma_f32_16x16x32_bf16(Ah[2][kt], b, a2, 0, 0, 0);   \
      a3 = __builtin_amdgcn_mfma_f32_16x16x32_bf16(Ah[3][kt], b, a3, 0, 0, 0);   \
    }                                                                            \
    _Pragma("unroll")                                                            \
    for (int kt = 0; kt < 4; kt++) {                                             \
      v8s b = __builtin_bit_cast(v8s, CUR[kt]);                                  \
      a0 = __builtin_amdgcn_mfma_f32_16x16x32_bf16(Ai[0][kt], b, a0, 0, 0, 0);   \
      a1 = __builtin_amdgcn_mfma_f32_16x16x32_bf16(Ai[1][kt], b, a1, 0, 0, 0);   \
      a2 = __builtin_amdgcn_mfma_f32_16x16x32_bf16(Ai[2][kt], b, a2, 0, 0, 0);   \
      a3 = __builtin_amdgcn_mfma_f32_16x16x32_bf16(Ai[3][kt], b, a3, 0, 0, 0);   \
    }                                                                            \
    _Pragma("unroll")                                                            \
    for (int r = 0; r < 4; r++) {                                                \
      float cn = sigf(a1[r]) * c4[r] + sigf(a0[r]) * tanh_(a2[r]);               \
      c4[r] = cn;                                                                \
      h4[r] = sigf(a3[r]) * tanh_(cn);                                           \
    }                                                                            \
    if (lr < 8) {                                                                \
      uint2 hp;                                                                  \
      hp.x = (unsigned)f2bf(h4[0]) | ((unsigned)f2bf(h4[1]) << 16);              \
      hp.y = (unsigned)f2bf(h4[2]) | ((unsigned)f2bf(h4[3]) << 16);              \
      *(uint2*)((char*)(HBW) + woff) = hp;                                       \
    }                                                                            \
    __syncthreads();                                                             \
  }

__global__ void __launch_bounds__(512) lstm1_k(
    const float* __restrict__ Wih1, const float* __restrict__ Whh1,
    const float* __restrict__ bih1, const float* __restrict__ bhh1,
    char* __restrict__ ws, int CH)
{
  const int tid = threadIdx.x;
  const int w = tid >> 6, l = tid & 63, lr = l & 15, g = l >> 4;
  const int bt = blockIdx.x;
  const int rowb = lr & 7;
  float* hstate = (float*)(ws + (512 << 10));
  float* cstate = (float*)(ws + (768 << 10));
  const char* y0c = ws + (1 << 20);
  __shared__ unsigned hbuf[2][512];

  v8s Ai[4][4], Ah[4][4]; v4f bias[4];
  #pragma unroll
  for (int t = 0; t < 4; t++) {
    const int gate0 = t * 128 + w * 16 + lr;
    #pragma unroll
    for (int kt = 0; kt < 4; kt++) {
      const float* pi = Wih1 + gate0 * Hn + kt * 32 + g * 8;
      const float* ph = Whh1 + gate0 * Hn + kt * 32 + g * 8;
      v8s ai, ah;
      #pragma unroll
      for (int i = 0; i < 8; i++) { ai[i] = (short)f2bf(pi[i]); ah[i] = (short)f2bf(ph[i]); }
      Ai[t][kt] = ai; Ah[t][kt] = ah;
    }
    const int gb = t * 128 + w * 16 + g * 4;
    v4f bb;
    #pragma unroll
    for (int r = 0; r < 4; r++) bb[r] = bih1[gb + r] + bhh1[gb + r];
    bias[t] = bb;
  }
  unsigned off_k[4];
  #pragma unroll
  for (int kt = 0; kt < 4; kt++)
    off_k[kt] = rowb * 256 + ((((unsigned)kt * 4 + g) ^ (unsigned)rowb) << 4);
  const int dimb = w * 16 + g * 4;
  const unsigned woff = lr * 256 + (((unsigned)dimb * 2) ^ ((unsigned)lr << 4));
  const size_t tb = (size_t)bt * 2048;

  float c4[4], h4[4];
  const int brow = bt * 8 + rowb;
  if (lr < 8) {
    const float4 hv = *(const float4*)(hstate + brow * Hn + dimb);
    const float4 cv = *(const float4*)(cstate + brow * Hn + dimb);
    c4[0] = cv.x; c4[1] = cv.y; c4[2] = cv.z; c4[3] = cv.w;
    uint2 hp;
    hp.x = (unsigned)f2bf(hv.x) | ((unsigned)f2bf(hv.y) << 16);
    hp.y = (unsigned)f2bf(hv.z) | ((unsigned)f2bf(hv.w) << 16);
    *(uint2*)((char*)hbuf[0] + woff) = hp;
  } else { c4[0] = c4[1] = c4[2] = c4[3] = 0.f; }
  h4[0] = h4[1] = h4[2] = h4[3] = 0.f;

  uint4 ih0[4], ih1[4];
  #pragma unroll
  for (int kt = 0; kt < 4; kt++) ih0[kt] = *(const uint4*)(y0c + tb + off_k[kt]);
  __syncthreads();

  for (int s = 0; s < CH; s += 2) {
    L1_BODY(hbuf[0], hbuf[1], ih0, ih1, s + 1)
    const int sn = (s + 2 < CH) ? s + 2 : CH - 1;
    L1_BODY(hbuf[1], hbuf[0], ih1, ih0, sn)
  }
  if (lr < 8) {
    *(float4*)(hstate + brow * Hn + dimb) = make_float4(h4[0], h4[1], h4[2], h4[3]);
    *(float4*)(cstate + brow * Hn + dimb) = make_float4(c4[0], c4[1], c4[2], c4[3]);
  }
}

// ---------------- classifier head + double softmax ----------------
__global__ void __launch_bounds__(128) cls_k(
    const char* __restrict__ ws, const float* __restrict__ W1, const float* __restrict__ b1,
    const float* __restrict__ W2, const float* __restrict__ b2,
    const float* __restrict__ W3, const float* __restrict__ b3, float* __restrict__ out)
{
  const float* h1 = (const float*)(ws + (512 << 10));
  const int row = blockIdx.x, tid = threadIdx.x;
  __shared__ float hs[128], z1[128], z2[64];
  hs[tid] = h1[row * 128 + tid];
  __syncthreads();
  float s = b1[tid];
  #pragma unroll 4
  for (int k = 0; k < 128; k++) s += hs[k] * W1[tid * 128 + k];
  z1[tid] = fmaxf(s, 0.f);
  __syncthreads();
  if (tid < 64) {
    float s2 = b2[tid];
    #pragma unroll 4
    for (int k = 0; k < 128; k++) s2 += z1[k] * W2[tid * 128 + k];
    z2[tid] = fmaxf(s2, 0.f);
  }
  __syncthreads();
  if (tid == 0) {
    float z3[6];
    #pragma unroll
    for (int j = 0; j < 6; j++) {
      float s3 = b3[j];
      for (int k = 0; k < 64; k++) s3 += z2[k] * W3[j * 64 + k];
      z3[j] = s3;
    }
    #pragma unroll
    for (int pass = 0; pass < 2; pass++) {
      float m = z3[0];
      #pragma unroll
      for (int j = 1; j < 6; j++) m = fmaxf(m, z3[j]);
      float se = 0.f;
      #pragma unroll
      for (int j = 0; j < 6; j++) { z3[j] = __builtin_amdgcn_exp2f((z3[j] - m) * 1.44269504f); se += z3[j]; }
      float inv = 1.f / se;
      #pragma unroll
      for (int j = 0; j < 6; j++) z3[j] *= inv;
    }
    #pragma unroll
    for (int j = 0; j < 6; j++) out[row * 6 + j] = z3[j];
  }
}

extern "C" void kernel_launch(void* const* d_in, const int* in_sizes, int n_in,
                              void* d_out, int out_size, void* d_ws, size_t ws_size,
                              hipStream_t stream)
{
  (void)in_sizes; (void)n_in; (void)out_size;
  const float* x    = (const float*)d_in[0];
  const float* Wih0 = (const float*)d_in[1];
  const float* Whh0 = (const float*)d_in[2];
  const float* bih0 = (const float*)d_in[3];
  const float* bhh0 = (const float*)d_in[4];
  const float* Wih1 = (const float*)d_in[5];
  const float* Whh1 = (const float*)d_in[6];
  const float* bih1 = (const float*)d_in[7];
  const float* bhh1 = (const float*)d_in[8];
  const float* W1 = (const float*)d_in[9];
  const float* b1 = (const float*)d_in[10];
  const float* W2 = (const float*)d_in[11];
  const float* b2 = (const float*)d_in[12];
  const float* W3 = (const float*)d_in[13];
  const float* b3 = (const float*)d_in[14];
  char* ws = (char*)d_ws;

  // y0 chunk buffer lives at ws+1MB; pick the largest chunk that fits.
  int CH = 32;
  for (int c = 2048; c >= 32; c >>= 1) {
    if ((size_t)(1 << 20) + (size_t)c * 131072 <= ws_size) { CH = c; break; }
  }
  hipMemsetAsync(ws, 0, 1 << 20, stream);  // zero h0,c0,h1,c1 states
  for (int t0 = 0; t0 < Tn; t0 += CH) {
    hipLaunchKernelGGL(lstm0_k, dim3(64), dim3(512), 0, stream,
                       x, Wih0, Whh0, bih0, bhh0, ws, t0, CH);
    hipLaunchKernelGGL(lstm1_k, dim3(64), dim3(512), 0, stream,
                       Wih1, Whh1, bih1, bhh1, ws, CH);
  }
  hipLaunchKernelGGL(cls_k, dim3(512), dim3(128), 0, stream,
                     ws, W1, b1, W2, b2, W3, b3, (float*)d_out);
}

// Round 3
// 3244.227 us; speedup vs baseline: 1.2249x; 1.2249x over previous
//
#include <hip/hip_runtime.h>

#define Tn 2048
#define Hn 128
#define L2E 1.4426950408889634f

typedef __attribute__((ext_vector_type(8))) short v8s;
typedef __attribute__((ext_vector_type(4))) float v4f;
typedef unsigned long long u64;

__device__ __forceinline__ unsigned short f2bf(float f) {
  unsigned u = __builtin_bit_cast(unsigned, f);
  return (unsigned short)((u + 0x7fffu + ((u >> 16) & 1u)) >> 16);
}
__device__ __forceinline__ unsigned cvtpk(float lo, float hi) {
  unsigned r;
  asm("v_cvt_pk_bf16_f32 %0, %1, %2" : "=v"(r) : "v"(lo), "v"(hi));
  return r;
}
// pre-scaled activations: weights/bias rows for i,f,o scaled by L2E; g rows by 2*L2E
__device__ __forceinline__ float sig_pre(float a) {   // a = L2E * x
  return __builtin_amdgcn_rcpf(1.f + __builtin_amdgcn_exp2f(-a));
}
__device__ __forceinline__ float tanh_pre(float a) {  // a = 2*L2E * x
  return 1.f - 2.f * __builtin_amdgcn_rcpf(1.f + __builtin_amdgcn_exp2f(a));
}
__device__ __forceinline__ float tanh_raw(float x) {  // unscaled input (cell state)
  return tanh_pre(2.f * L2E * x);
}

#define CELL()                                                        \
  _Pragma("unroll")                                                   \
  for (int r = 0; r < 4; r++) {                                       \
    float cn = sig_pre(a1[r]) * c4[r] + sig_pre(a0[r]) * tanh_pre(a2[r]); \
    c4[r] = cn;                                                       \
    h4[r] = sig_pre(a3[r]) * tanh_raw(cn);                            \
  }

// ws layout: [0,256K) h1_final f32 | [256K,+4K) prog0[64] (64B stride)
//            [260K,+4K) consp[64] (64B stride) | [1M, 1M+R*128K) y0 ring
__global__ void __launch_bounds__(512) lstm_pipe_k(
    const float* __restrict__ x,
    const float* __restrict__ Wih0, const float* __restrict__ Whh0,
    const float* __restrict__ bih0, const float* __restrict__ bhh0,
    const float* __restrict__ Wih1, const float* __restrict__ Whh1,
    const float* __restrict__ bih1, const float* __restrict__ bhh1,
    char* __restrict__ ws, int rmask)
{
  const int tid = threadIdx.x;
  const int w = tid >> 6, l = tid & 63, lr = l & 15, g = l >> 4;
  const int role = blockIdx.x >> 6;
  const int b = blockIdx.x & 63;
  const int rowb = lr & 7;
  unsigned* prog0 = (unsigned*)(ws + (256 << 10) + b * 64);
  unsigned* consp = (unsigned*)(ws + (256 << 10) + 4096 + b * 64);
  char* y0r = ws + (1 << 20);
  const float wsc[4] = {L2E, L2E, 2.f * L2E, L2E};

  unsigned off_k[4];
  #pragma unroll
  for (int kt = 0; kt < 4; kt++)
    off_k[kt] = rowb * 256 + ((((unsigned)kt * 4 + g) ^ (unsigned)rowb) << 4);
  const int dimb = w * 16 + g * 4;
  const unsigned woff = lr * 256 + (((unsigned)dimb * 2) ^ ((unsigned)lr << 4));
  float c4[4] = {0.f, 0.f, 0.f, 0.f}, h4[4] = {0.f, 0.f, 0.f, 0.f};

  if (role == 0) {
    // ---------------- layer 0 producer ----------------
    __shared__ unsigned hbuf[2][512];
    __shared__ unsigned fbuf[2][32][8];
    v8s A[4][4], Ain[4]; v4f bias[4];
    #pragma unroll
    for (int t = 0; t < 4; t++) {
      const int gate0 = t * 128 + w * 16 + lr;
      #pragma unroll
      for (int kt = 0; kt < 4; kt++) {
        const float* p = Whh0 + gate0 * Hn + kt * 32 + g * 8;
        v8s a;
        #pragma unroll
        for (int i = 0; i < 8; i++) a[i] = (short)f2bf(p[i] * wsc[t]);
        A[t][kt] = a;
      }
      v8s ai = {0,0,0,0,0,0,0,0};
      if (g == 0) {
        ai[0] = (short)f2bf(Wih0[gate0 * 2] * wsc[t]);
        ai[1] = (short)f2bf(Wih0[gate0 * 2 + 1] * wsc[t]);
      }
      Ain[t] = ai;
      const int gb = t * 128 + w * 16 + g * 4;
      v4f bb;
      #pragma unroll
      for (int r = 0; r < 4; r++) bb[r] = (bih0[gb + r] + bhh0[gb + r]) * wsc[t];
      bias[t] = bb;
    }
    hbuf[0][tid] = 0;

    const int sb_b = tid >> 6, sb_t = (tid & 63) >> 1, sb_c = tid & 1;
    auto stage = [&](int sbase) {
      const float* xp = x + ((size_t)(b * 8 + sb_b) * Tn + (sbase + sb_t)) * 6 + sb_c * 3;
      float v0 = xp[0], v1 = xp[1], v2 = xp[2];
      unsigned short nb = f2bf(__builtin_amdgcn_sqrtf(v0 * v0 + v1 * v1 + v2 * v2));
      ((unsigned short*)fbuf[(sbase >> 5) & 1])[(sb_t * 8 + sb_b) * 2 + sb_c] = nb;
    };
    stage(0);
    __syncthreads();

    u64 pend = 0;
    for (int s = 0; s < Tn; ++s) {
      // ring flow control (poll once per 256 steps when wrap possible)
      if ((s & 255) == 0 && s + 256 > rmask + 1) {
        if (tid == 0) {
          unsigned need = (unsigned)(s + 256 - (rmask + 1));
          while (__hip_atomic_load(consp, __ATOMIC_ACQUIRE, __HIP_MEMORY_SCOPE_AGENT) < need) {}
        }
        __syncthreads();
      }
      // deferred y0 store for step s-1 (ack hides under this step's compute)
      if (s > 0 && lr < 8)
        __hip_atomic_store((u64*)(y0r + (((size_t)((s - 1) & rmask)) * 64 + b) * 2048 + woff),
                           pend, __ATOMIC_RELAXED, __HIP_MEMORY_SCOPE_AGENT);
      if ((s & 31) == 0 && s + 32 < Tn) stage(s + 32);

      uint4 Bf[4];
      const char* hbR = (const char*)hbuf[s & 1];
      #pragma unroll
      for (int kt = 0; kt < 4; kt++) Bf[kt] = *(const uint4*)(hbR + off_k[kt]);
      const unsigned fpk = fbuf[(s >> 5) & 1][s & 31][rowb];
      v8s bin = {0,0,0,0,0,0,0,0};
      if (g == 0) { bin[0] = (short)(fpk & 0xffffu); bin[1] = (short)(fpk >> 16); }
      v4f a0 = bias[0], a1 = bias[1], a2 = bias[2], a3 = bias[3];
      #pragma unroll
      for (int kt = 0; kt < 4; kt++) {
        v8s bb = __builtin_bit_cast(v8s, Bf[kt]);
        a0 = __builtin_amdgcn_mfma_f32_16x16x32_bf16(A[0][kt], bb, a0, 0, 0, 0);
        a1 = __builtin_amdgcn_mfma_f32_16x16x32_bf16(A[1][kt], bb, a1, 0, 0, 0);
        a2 = __builtin_amdgcn_mfma_f32_16x16x32_bf16(A[2][kt], bb, a2, 0, 0, 0);
        a3 = __builtin_amdgcn_mfma_f32_16x16x32_bf16(A[3][kt], bb, a3, 0, 0, 0);
      }
      a0 = __builtin_amdgcn_mfma_f32_16x16x32_bf16(Ain[0], bin, a0, 0, 0, 0);
      a1 = __builtin_amdgcn_mfma_f32_16x16x32_bf16(Ain[1], bin, a1, 0, 0, 0);
      a2 = __builtin_amdgcn_mfma_f32_16x16x32_bf16(Ain[2], bin, a2, 0, 0, 0);
      a3 = __builtin_amdgcn_mfma_f32_16x16x32_bf16(Ain[3], bin, a3, 0, 0, 0);
      CELL();
      if (lr < 8) {
        unsigned px = cvtpk(h4[0], h4[1]), py = cvtpk(h4[2], h4[3]);
        *(uint2*)((char*)hbuf[(s + 1) & 1] + woff) = make_uint2(px, py);
        pend = ((u64)py << 32) | px;
      }
      __syncthreads();
      if (tid == 0 && s > 0)
        __hip_atomic_store(prog0, (unsigned)s, __ATOMIC_RELEASE, __HIP_MEMORY_SCOPE_AGENT);
    }
    if (lr < 8)
      __hip_atomic_store((u64*)(y0r + (((size_t)((Tn - 1) & rmask)) * 64 + b) * 2048 + woff),
                         pend, __ATOMIC_RELAXED, __HIP_MEMORY_SCOPE_AGENT);
    __syncthreads();
    if (tid == 0)
      __hip_atomic_store(prog0, (unsigned)Tn, __ATOMIC_RELEASE, __HIP_MEMORY_SCOPE_AGENT);
  } else {
    // ---------------- layer 1 consumer ----------------
    __shared__ unsigned h1buf[2][512];
    __shared__ u64 y0lds[2][256];
    v8s Ai[4][4], Ah[4][4]; v4f bias[4];
    #pragma unroll
    for (int t = 0; t < 4; t++) {
      const int gate0 = t * 128 + w * 16 + lr;
      #pragma unroll
      for (int kt = 0; kt < 4; kt++) {
        const float* pi = Wih1 + gate0 * Hn + kt * 32 + g * 8;
        const float* ph = Whh1 + gate0 * Hn + kt * 32 + g * 8;
        v8s ai, ah;
        #pragma unroll
        for (int i = 0; i < 8; i++) {
          ai[i] = (short)f2bf(pi[i] * wsc[t]);
          ah[i] = (short)f2bf(ph[i] * wsc[t]);
        }
        Ai[t][kt] = ai; Ah[t][kt] = ah;
      }
      const int gb = t * 128 + w * 16 + g * 4;
      v4f bb;
      #pragma unroll
      for (int r = 0; r < 4; r++) bb[r] = (bih1[gb + r] + bhh1[gb + r]) * wsc[t];
      bias[t] = bb;
    }
    h1buf[0][tid] = 0;
    if (tid == 0) {
      while (__hip_atomic_load(prog0, __ATOMIC_ACQUIRE, __HIP_MEMORY_SCOPE_AGENT) < 2u) {}
    }
    __syncthreads();
    if (tid < 256)
      y0lds[0][tid] = __hip_atomic_load((const u64*)(y0r + (size_t)b * 2048) + tid,
                                        __ATOMIC_RELAXED, __HIP_MEMORY_SCOPE_AGENT);
    __syncthreads();

    for (int s = 0; s < Tn; ++s) {
      u64 pre = 0;
      if (tid < 256 && s + 1 < Tn)
        pre = __hip_atomic_load(
            (const u64*)(y0r + (((size_t)((s + 1) & rmask)) * 64 + b) * 2048) + tid,
            __ATOMIC_RELAXED, __HIP_MEMORY_SCOPE_AGENT);
      uint4 Yf[4], Bf[4];
      const char* ybR = (const char*)y0lds[s & 1];
      const char* hbR = (const char*)h1buf[s & 1];
      #pragma unroll
      for (int kt = 0; kt < 4; kt++) {
        Yf[kt] = *(const uint4*)(ybR + off_k[kt]);
        Bf[kt] = *(const uint4*)(hbR + off_k[kt]);
      }
      v4f a0 = bias[0], a1 = bias[1], a2 = bias[2], a3 = bias[3];
      #pragma unroll
      for (int kt = 0; kt < 4; kt++) {
        v8s bb = __builtin_bit_cast(v8s, Bf[kt]);
        a0 = __builtin_amdgcn_mfma_f32_16x16x32_bf16(Ah[0][kt], bb, a0, 0, 0, 0);
        a1 = __builtin_amdgcn_mfma_f32_16x16x32_bf16(Ah[1][kt], bb, a1, 0, 0, 0);
        a2 = __builtin_amdgcn_mfma_f32_16x16x32_bf16(Ah[2][kt], bb, a2, 0, 0, 0);
        a3 = __builtin_amdgcn_mfma_f32_16x16x32_bf16(Ah[3][kt], bb, a3, 0, 0, 0);
      }
      #pragma unroll
      for (int kt = 0; kt < 4; kt++) {
        v8s bb = __builtin_bit_cast(v8s, Yf[kt]);
        a0 = __builtin_amdgcn_mfma_f32_16x16x32_bf16(Ai[0][kt], bb, a0, 0, 0, 0);
        a1 = __builtin_amdgcn_mfma_f32_16x16x32_bf16(Ai[1][kt], bb, a1, 0, 0, 0);
        a2 = __builtin_amdgcn_mfma_f32_16x16x32_bf16(Ai[2][kt], bb, a2, 0, 0, 0);
        a3 = __builtin_amdgcn_mfma_f32_16x16x32_bf16(Ai[3][kt], bb, a3, 0, 0, 0);
      }
      CELL();
      if (tid < 256 && s + 1 < Tn) y0lds[(s + 1) & 1][tid] = pre;
      if (lr < 8) {
        unsigned px = cvtpk(h4[0], h4[1]), py = cvtpk(h4[2], h4[3]);
        *(uint2*)((char*)h1buf[(s + 1) & 1] + woff) = make_uint2(px, py);
      }
      if (tid == 0) {
        unsigned tgt = (unsigned)(s + 3 < Tn ? s + 3 : Tn);
        while (__hip_atomic_load(prog0, __ATOMIC_ACQUIRE, __HIP_MEMORY_SCOPE_AGENT) < tgt) {}
        if ((s & 63) == 63)
          __hip_atomic_store(consp, (unsigned)s, __ATOMIC_RELEASE, __HIP_MEMORY_SCOPE_AGENT);
      }
      __syncthreads();
    }
    if (lr < 8)
      *(float4*)((float*)ws + (size_t)(b * 8 + rowb) * Hn + dimb) =
          make_float4(h4[0], h4[1], h4[2], h4[3]);
  }
}

// ---------------- classifier head + double softmax ----------------
__global__ void __launch_bounds__(128) cls_k(
    const char* __restrict__ ws, const float* __restrict__ W1, const float* __restrict__ b1,
    const float* __restrict__ W2, const float* __restrict__ b2,
    const float* __restrict__ W3, const float* __restrict__ b3, float* __restrict__ out)
{
  const float* h1 = (const float*)ws;
  const int row = blockIdx.x, tid = threadIdx.x;
  __shared__ float hs[128], z1[128], z2[64];
  hs[tid] = h1[row * 128 + tid];
  __syncthreads();
  float s = b1[tid];
  #pragma unroll 4
  for (int k = 0; k < 128; k++) s += hs[k] * W1[tid * 128 + k];
  z1[tid] = fmaxf(s, 0.f);
  __syncthreads();
  if (tid < 64) {
    float s2 = b2[tid];
    #pragma unroll 4
    for (int k = 0; k < 128; k++) s2 += z1[k] * W2[tid * 128 + k];
    z2[tid] = fmaxf(s2, 0.f);
  }
  __syncthreads();
  if (tid == 0) {
    float z3[6];
    #pragma unroll
    for (int j = 0; j < 6; j++) {
      float s3 = b3[j];
      for (int k = 0; k < 64; k++) s3 += z2[k] * W3[j * 64 + k];
      z3[j] = s3;
    }
    #pragma unroll
    for (int pass = 0; pass < 2; pass++) {
      float m = z3[0];
      #pragma unroll
      for (int j = 1; j < 6; j++) m = fmaxf(m, z3[j]);
      float se = 0.f;
      #pragma unroll
      for (int j = 0; j < 6; j++) {
        z3[j] = __builtin_amdgcn_exp2f((z3[j] - m) * L2E);
        se += z3[j];
      }
      float inv = 1.f / se;
      #pragma unroll
      for (int j = 0; j < 6; j++) z3[j] *= inv;
    }
    #pragma unroll
    for (int j = 0; j < 6; j++) out[row * 6 + j] = z3[j];
  }
}

extern "C" void kernel_launch(void* const* d_in, const int* in_sizes, int n_in,
                              void* d_out, int out_size, void* d_ws, size_t ws_size,
                              hipStream_t stream)
{
  (void)in_sizes; (void)n_in; (void)out_size;
  const float* x    = (const float*)d_in[0];
  const float* Wih0 = (const float*)d_in[1];
  const float* Whh0 = (const float*)d_in[2];
  const float* bih0 = (const float*)d_in[3];
  const float* bhh0 = (const float*)d_in[4];
  const float* Wih1 = (const float*)d_in[5];
  const float* Whh1 = (const float*)d_in[6];
  const float* bih1 = (const float*)d_in[7];
  const float* bhh1 = (const float*)d_in[8];
  const float* W1 = (const float*)d_in[9];
  const float* b1 = (const float*)d_in[10];
  const float* W2 = (const float*)d_in[11];
  const float* b2 = (const float*)d_in[12];
  const float* W3 = (const float*)d_in[13];
  const float* b3 = (const float*)d_in[14];
  char* ws = (char*)d_ws;

  // y0 ring: largest power-of-2 step count that fits after the 1MB header.
  int R = 32;
  for (int c = Tn; c >= 32; c >>= 1) {
    if ((size_t)(1 << 20) + (size_t)c * 131072 <= ws_size) { R = c; break; }
  }
  hipMemsetAsync(ws + (256 << 10), 0, 8192, stream);  // prog0 + consp flags
  hipLaunchKernelGGL(lstm_pipe_k, dim3(128), dim3(512), 0, stream,
                     x, Wih0, Whh0, bih0, bhh0, Wih1, Whh1, bih1, bhh1, ws, R - 1);
  hipLaunchKernelGGL(cls_k, dim3(512), dim3(128), 0, stream,
                     ws, W1, b1, W2, b2, W3, b3, (float*)d_out);
}

// Round 5
// 2160.851 us; speedup vs baseline: 1.8391x; 1.5014x over previous
//
#include <hip/hip_runtime.h>

#define Tn 2048
#define Hn 128
#define L2E 1.4426950408889634f

typedef __attribute__((ext_vector_type(8))) short v8s;
typedef __attribute__((ext_vector_type(4))) float v4f;
typedef unsigned long long u64;

__device__ __forceinline__ unsigned short f2bf(float f) {
  unsigned u = __builtin_bit_cast(unsigned, f);
  return (unsigned short)((u + 0x7fffu + ((u >> 16) & 1u)) >> 16);
}
__device__ __forceinline__ unsigned cvtpk(float lo, float hi) {
  unsigned r;
  asm("v_cvt_pk_bf16_f32 %0, %1, %2" : "=v"(r) : "v"(lo), "v"(hi));
  return r;
}
__device__ __forceinline__ float sig_pre(float a) {   // a = L2E * x
  return __builtin_amdgcn_rcpf(1.f + __builtin_amdgcn_exp2f(-a));
}
__device__ __forceinline__ float tanh_pre(float a) {  // a = 2*L2E * x
  return 1.f - 2.f * __builtin_amdgcn_rcpf(1.f + __builtin_amdgcn_exp2f(a));
}
__device__ __forceinline__ float tanh_raw(float x) {
  return tanh_pre(2.f * L2E * x);
}

#define CELL()                                                            \
  _Pragma("unroll")                                                       \
  for (int r = 0; r < 4; r++) {                                           \
    float cn = sig_pre(a1[r]) * c4[r] + sig_pre(a0[r]) * tanh_pre(a2[r]); \
    c4[r] = cn;                                                           \
    h4[r] = sig_pre(a3[r]) * tanh_raw(cn);                                \
  }

// raw barrier: LDS drained, VMEM ops stay in flight across it
#define BAR_FAST()                                           \
  do {                                                       \
    asm volatile("s_waitcnt lgkmcnt(0)" ::: "memory");       \
    __builtin_amdgcn_s_barrier();                            \
    asm volatile("" ::: "memory");                           \
  } while (0)

// ws layout: [0,256K) h1_final f32 | [256K,+4K) prog0[64] (64B stride)
//            [260K,+4K) consp[64] (64B stride) | [1M, 1M+R*128K) y0 ring
// prog0 = P  =>  y0 slots t <= P-1 are durably visible (agent scope).
// consp = V  =>  consumer has finished reading y0 slots <= V.
__global__ void __launch_bounds__(512) lstm_pipe_k(
    const float* __restrict__ x,
    const float* __restrict__ Wih0, const float* __restrict__ Whh0,
    const float* __restrict__ bih0, const float* __restrict__ bhh0,
    const float* __restrict__ Wih1, const float* __restrict__ Whh1,
    const float* __restrict__ bih1, const float* __restrict__ bhh1,
    char* __restrict__ ws, int rmask)
{
  const int tid = threadIdx.x;
  const int w = tid >> 6, l = tid & 63, lr = l & 15, g = l >> 4;
  const int role = blockIdx.x >> 6;
  const int b = blockIdx.x & 63;
  const int rowb = lr & 7;
  unsigned* prog0 = (unsigned*)(ws + (256 << 10) + b * 64);
  unsigned* consp = (unsigned*)(ws + (256 << 10) + 4096 + b * 64);
  char* y0r = ws + (1 << 20);
  const float wsc[4] = {L2E, L2E, 2.f * L2E, L2E};

  unsigned off_k[4];
  #pragma unroll
  for (int kt = 0; kt < 4; kt++)
    off_k[kt] = rowb * 256 + ((((unsigned)kt * 4 + g) ^ (unsigned)rowb) << 4);
  const int dimb = w * 16 + g * 4;
  const unsigned woff = lr * 256 + (((unsigned)dimb * 2) ^ ((unsigned)lr << 4));
  float c4[4] = {0.f, 0.f, 0.f, 0.f}, h4[4] = {0.f, 0.f, 0.f, 0.f};

  if (role == 0) {
    // ---------------- layer 0 producer ----------------
    __shared__ unsigned hbuf[2][512];
    __shared__ unsigned fbuf[2][32][8];
    v8s A[4][4], Ain[4]; v4f bias[4];
    #pragma unroll
    for (int t = 0; t < 4; t++) {
      const int gate0 = t * 128 + w * 16 + lr;
      #pragma unroll
      for (int kt = 0; kt < 4; kt++) {
        const float* p = Whh0 + gate0 * Hn + kt * 32 + g * 8;
        v8s a;
        #pragma unroll
        for (int i = 0; i < 8; i++) a[i] = (short)f2bf(p[i] * wsc[t]);
        A[t][kt] = a;
      }
      v8s ai = {0,0,0,0,0,0,0,0};
      if (g == 0) {
        ai[0] = (short)f2bf(Wih0[gate0 * 2] * wsc[t]);
        ai[1] = (short)f2bf(Wih0[gate0 * 2 + 1] * wsc[t]);
      }
      Ain[t] = ai;
      const int gb = t * 128 + w * 16 + g * 4;
      v4f bb;
      #pragma unroll
      for (int r = 0; r < 4; r++) bb[r] = (bih0[gb + r] + bhh0[gb + r]) * wsc[t];
      bias[t] = bb;
    }
    hbuf[0][tid] = 0;

    const int sb_b = tid >> 6, sb_t = (tid & 63) >> 1, sb_c = tid & 1;
    auto stage = [&](int sbase) {
      const float* xp = x + ((size_t)(b * 8 + sb_b) * Tn + (sbase + sb_t)) * 6 + sb_c * 3;
      float v0 = xp[0], v1 = xp[1], v2 = xp[2];
      unsigned short nb = f2bf(__builtin_amdgcn_sqrtf(v0 * v0 + v1 * v1 + v2 * v2));
      ((unsigned short*)fbuf[(sbase >> 5) & 1])[(sb_t * 8 + sb_b) * 2 + sb_c] = nb;
    };
    stage(0);
    __syncthreads();

    u64 pend = 0;
    for (int s = 0; s < Tn; ++s) {
      // ring backpressure (rare; blocking OK)
      if ((s & 63) == 0 && s + 64 > rmask + 1) {
        if (tid == 0) {
          unsigned need = (unsigned)(s + 64 - (rmask + 1));
          while (__hip_atomic_load(consp, __ATOMIC_ACQUIRE, __HIP_MEMORY_SCOPE_AGENT) < need) {}
        }
        __syncthreads();
      }
      // deferred y0 store for step s-1; stays in flight across barriers
      if (s > 0 && lr < 8)
        __hip_atomic_store((u64*)(y0r + (((size_t)((s - 1) & rmask)) * 64 + b) * 2048 + woff),
                           pend, __ATOMIC_RELAXED, __HIP_MEMORY_SCOPE_AGENT);
      if ((s & 31) == 0 && s + 32 < Tn) stage(s + 32);

      uint4 Bf[4];
      const char* hbR = (const char*)hbuf[s & 1];
      #pragma unroll
      for (int kt = 0; kt < 4; kt++) Bf[kt] = *(const uint4*)(hbR + off_k[kt]);
      const unsigned fpk = fbuf[(s >> 5) & 1][s & 31][rowb];
      v8s bin = {0,0,0,0,0,0,0,0};
      if (g == 0) { bin[0] = (short)(fpk & 0xffffu); bin[1] = (short)(fpk >> 16); }
      v4f a0 = bias[0], a1 = bias[1], a2 = bias[2], a3 = bias[3];
      #pragma unroll
      for (int kt = 0; kt < 4; kt++) {
        v8s bb = __builtin_bit_cast(v8s, Bf[kt]);
        a0 = __builtin_amdgcn_mfma_f32_16x16x32_bf16(A[0][kt], bb, a0, 0, 0, 0);
        a1 = __builtin_amdgcn_mfma_f32_16x16x32_bf16(A[1][kt], bb, a1, 0, 0, 0);
        a2 = __builtin_amdgcn_mfma_f32_16x16x32_bf16(A[2][kt], bb, a2, 0, 0, 0);
        a3 = __builtin_amdgcn_mfma_f32_16x16x32_bf16(A[3][kt], bb, a3, 0, 0, 0);
      }
      a0 = __builtin_amdgcn_mfma_f32_16x16x32_bf16(Ain[0], bin, a0, 0, 0, 0);
      a1 = __builtin_amdgcn_mfma_f32_16x16x32_bf16(Ain[1], bin, a1, 0, 0, 0);
      a2 = __builtin_amdgcn_mfma_f32_16x16x32_bf16(Ain[2], bin, a2, 0, 0, 0);
      a3 = __builtin_amdgcn_mfma_f32_16x16x32_bf16(Ain[3], bin, a3, 0, 0, 0);
      CELL();
      if (lr < 8) {
        unsigned px = cvtpk(h4[0], h4[1]), py = cvtpk(h4[2], h4[3]);
        *(uint2*)((char*)hbuf[(s + 1) & 1] + woff) = make_uint2(px, py);
        pend = ((u64)py << 32) | px;
      }
      asm volatile("s_waitcnt lgkmcnt(0)" ::: "memory");
      if ((s & 3) == 3) asm volatile("s_waitcnt vmcnt(4)" ::: "memory");
      __builtin_amdgcn_s_barrier();
      asm volatile("" ::: "memory");
      // all waves passed vmcnt(4): stores for slots <= s-5 retired -> P = s-4
      if (tid == 0 && (s & 3) == 3 && s >= 7)
        __hip_atomic_store(prog0, (unsigned)(s - 4), __ATOMIC_RELAXED, __HIP_MEMORY_SCOPE_AGENT);
    }
    if (lr < 8)
      __hip_atomic_store((u64*)(y0r + (((size_t)((Tn - 1) & rmask)) * 64 + b) * 2048 + woff),
                         pend, __ATOMIC_RELAXED, __HIP_MEMORY_SCOPE_AGENT);
    asm volatile("s_waitcnt vmcnt(0)" ::: "memory");
    __builtin_amdgcn_s_barrier();
    asm volatile("" ::: "memory");
    if (tid == 0)
      __hip_atomic_store(prog0, (unsigned)(Tn + 64), __ATOMIC_RELAXED, __HIP_MEMORY_SCOPE_AGENT);
  } else {
    // ---------------- layer 1 consumer ----------------
    __shared__ unsigned h1buf[2][512];
    __shared__ u64 y0lds[2][256];
    __shared__ unsigned sh_prog;
    v8s Ai[4][4], Ah[4][4]; v4f bias[4];
    #pragma unroll
    for (int t = 0; t < 4; t++) {
      const int gate0 = t * 128 + w * 16 + lr;
      #pragma unroll
      for (int kt = 0; kt < 4; kt++) {
        const float* pi = Wih1 + gate0 * Hn + kt * 32 + g * 8;
        const float* ph = Whh1 + gate0 * Hn + kt * 32 + g * 8;
        v8s ai, ah;
        #pragma unroll
        for (int i = 0; i < 8; i++) {
          ai[i] = (short)f2bf(pi[i] * wsc[t]);
          ah[i] = (short)f2bf(ph[i] * wsc[t]);
        }
        Ai[t][kt] = ai; Ah[t][kt] = ah;
      }
      const int gb = t * 128 + w * 16 + g * 4;
      v4f bb;
      #pragma unroll
      for (int r = 0; r < 4; r++) bb[r] = (bih1[gb + r] + bhh1[gb + r]) * wsc[t];
      bias[t] = bb;
    }
    h1buf[0][tid] = 0;
    if (tid == 0) sh_prog = 0;
    __syncthreads();

    auto ld_y0 = [&](int t) {
      return __hip_atomic_load(
          (const u64*)(y0r + (((size_t)(t & rmask)) * 64 + b) * 2048) + tid,
          __ATOMIC_RELAXED, __HIP_MEMORY_SCOPE_AGENT);
    };

    unsigned shP = 0;
    for (;;) {  // wait P >= 4 (slots 0..3 valid)
      if (tid == 0) sh_prog = __hip_atomic_load(prog0, __ATOMIC_ACQUIRE, __HIP_MEMORY_SCOPE_AGENT);
      __syncthreads();
      shP = sh_prog;
      __syncthreads();
      if (shP >= 4u) break;
    }
    u64 A_ = 0, B_ = 0;
    if (tid < 256) {
      u64 C_ = ld_y0(0);
      A_ = ld_y0(1);
      B_ = ld_y0(2);
      y0lds[0][tid] = C_;
    }
    __syncthreads();
    unsigned pollreg = 0;

#define STEP1(S)                                                                 \
  {                                                                              \
    uint4 Yf[4], Bf[4];                                                          \
    const char* ybR = (const char*)y0lds[(S) & 1];                               \
    const char* hbR = (const char*)h1buf[(S) & 1];                               \
    _Pragma("unroll")                                                            \
    for (int kt = 0; kt < 4; kt++) {                                             \
      Yf[kt] = *(const uint4*)(ybR + off_k[kt]);                                 \
      Bf[kt] = *(const uint4*)(hbR + off_k[kt]);                                 \
    }                                                                            \
    v4f a0 = bias[0], a1 = bias[1], a2 = bias[2], a3 = bias[3];                  \
    _Pragma("unroll")                                                            \
    for (int kt = 0; kt < 4; kt++) {                                             \
      v8s bb = __builtin_bit_cast(v8s, Bf[kt]);                                  \
      a0 = __builtin_amdgcn_mfma_f32_16x16x32_bf16(Ah[0][kt], bb, a0, 0, 0, 0);  \
      a1 = __builtin_amdgcn_mfma_f32_16x16x32_bf16(Ah[1][kt], bb, a1, 0, 0, 0);  \
      a2 = __builtin_amdgcn_mfma_f32_16x16x32_bf16(Ah[2][kt], bb, a2, 0, 0, 0);  \
      a3 = __builtin_amdgcn_mfma_f32_16x16x32_bf16(Ah[3][kt], bb, a3, 0, 0, 0);  \
    }                                                                            \
    _Pragma("unroll")                                                            \
    for (int kt = 0; kt < 4; kt++) {                                             \
      v8s bb = __builtin_bit_cast(v8s, Yf[kt]);                                  \
      a0 = __builtin_amdgcn_mfma_f32_16x16x32_bf16(Ai[0][kt], bb, a0, 0, 0, 0);  \
      a1 = __builtin_amdgcn_mfma_f32_16x16x32_bf16(Ai[1][kt], bb, a1, 0, 0, 0);  \
      a2 = __builtin_amdgcn_mfma_f32_16x16x32_bf16(Ai[2][kt], bb, a2, 0, 0, 0);  \
      a3 = __builtin_amdgcn_mfma_f32_16x16x32_bf16(Ai[3][kt], bb, a3, 0, 0, 0);  \
    }                                                                            \
    CELL();                                                                      \
    if (lr < 8) {                                                                \
      unsigned px = cvtpk(h4[0], h4[1]), py = cvtpk(h4[2], h4[3]);               \
      *(uint2*)((char*)h1buf[((S) + 1) & 1] + woff) = make_uint2(px, py);        \
    }                                                                            \
  }

    for (int c = 0; c < Tn; c += 2) {
      const unsigned need = (unsigned)((c + 5 < Tn) ? c + 5 : Tn);
      if (shP < need) {  // blocking catch-up (ramp only)
        for (;;) {
          if (tid == 0) sh_prog = __hip_atomic_load(prog0, __ATOMIC_ACQUIRE, __HIP_MEMORY_SCOPE_AGENT);
          __syncthreads();
          shP = sh_prog;
          __syncthreads();
          if (shP >= need) break;
        }
      }
      if (tid == 0) pollreg = __hip_atomic_load(prog0, __ATOMIC_RELAXED, __HIP_MEMORY_SCOPE_AGENT);
      // ---- step c ----
      if (tid < 256) {
        y0lds[(c + 1) & 1][tid] = A_;                 // slot c+1 (loaded 2 steps ago)
        A_ = ld_y0(c + 3 < Tn ? c + 3 : Tn - 1);      // issue slot c+3
      }
      STEP1(c);
      BAR_FAST();
      // ---- step c+1 ----
      if (tid < 256) {
        y0lds[c & 1][tid] = B_;                       // slot c+2
        B_ = ld_y0(c + 4 < Tn ? c + 4 : Tn - 1);      // issue slot c+4
      }
      STEP1(c + 1);
      if (tid == 0) sh_prog = pollreg;                // land the non-blocking poll
      BAR_FAST();
      shP = sh_prog;
      if (tid == 0 && (c & 63) == 62)
        __hip_atomic_store(consp, (unsigned)(c - 1), __ATOMIC_RELAXED, __HIP_MEMORY_SCOPE_AGENT);
    }
#undef STEP1
    if (lr < 8)
      *(float4*)((float*)ws + (size_t)(b * 8 + rowb) * Hn + dimb) =
          make_float4(h4[0], h4[1], h4[2], h4[3]);
  }
}

// ---------------- classifier head + double softmax ----------------
__global__ void __launch_bounds__(128) cls_k(
    const char* __restrict__ ws, const float* __restrict__ W1, const float* __restrict__ b1,
    const float* __restrict__ W2, const float* __restrict__ b2,
    const float* __restrict__ W3, const float* __restrict__ b3, float* __restrict__ out)
{
  const float* h1 = (const float*)ws;
  const int row = blockIdx.x, tid = threadIdx.x;
  __shared__ float hs[128], z1[128], z2[64];
  hs[tid] = h1[row * 128 + tid];
  __syncthreads();
  float s = b1[tid];
  #pragma unroll 4
  for (int k = 0; k < 128; k++) s += hs[k] * W1[tid * 128 + k];
  z1[tid] = fmaxf(s, 0.f);
  __syncthreads();
  if (tid < 64) {
    float s2 = b2[tid];
    #pragma unroll 4
    for (int k = 0; k < 128; k++) s2 += z1[k] * W2[tid * 128 + k];
    z2[tid] = fmaxf(s2, 0.f);
  }
  __syncthreads();
  if (tid == 0) {
    float z3[6];
    #pragma unroll
    for (int j = 0; j < 6; j++) {
      float s3 = b3[j];
      for (int k = 0; k < 64; k++) s3 += z2[k] * W3[j * 64 + k];
      z3[j] = s3;
    }
    #pragma unroll
    for (int pass = 0; pass < 2; pass++) {
      float m = z3[0];
      #pragma unroll
      for (int j = 1; j < 6; j++) m = fmaxf(m, z3[j]);
      float se = 0.f;
      #pragma unroll
      for (int j = 0; j < 6; j++) {
        z3[j] = __builtin_amdgcn_exp2f((z3[j] - m) * L2E);
        se += z3[j];
      }
      float inv = 1.f / se;
      #pragma unroll
      for (int j = 0; j < 6; j++) z3[j] *= inv;
    }
    #pragma unroll
    for (int j = 0; j < 6; j++) out[row * 6 + j] = z3[j];
  }
}

extern "C" void kernel_launch(void* const* d_in, const int* in_sizes, int n_in,
                              void* d_out, int out_size, void* d_ws, size_t ws_size,
                              hipStream_t stream)
{
  (void)in_sizes; (void)n_in; (void)out_size;
  const float* x    = (const float*)d_in[0];
  const float* Wih0 = (const float*)d_in[1];
  const float* Whh0 = (const float*)d_in[2];
  const float* bih0 = (const float*)d_in[3];
  const float* bhh0 = (const float*)d_in[4];
  const float* Wih1 = (const float*)d_in[5];
  const float* Whh1 = (const float*)d_in[6];
  const float* bih1 = (const float*)d_in[7];
  const float* bhh1 = (const float*)d_in[8];
  const float* W1 = (const float*)d_in[9];
  const float* b1 = (const float*)d_in[10];
  const float* W2 = (const float*)d_in[11];
  const float* b2 = (const float*)d_in[12];
  const float* W3 = (const float*)d_in[13];
  const float* b3 = (const float*)d_in[14];
  char* ws = (char*)d_ws;

  // y0 ring: largest power-of-2 step count that fits; floor 256 (deadlock margin ~140)
  int R = 256;
  for (int c = Tn; c >= 256; c >>= 1) {
    if ((size_t)(1 << 20) + (size_t)c * 131072 <= ws_size) { R = c; break; }
  }
  hipMemsetAsync(ws + (256 << 10), 0, 8192, stream);  // prog0 + consp flags
  hipLaunchKernelGGL(lstm_pipe_k, dim3(128), dim3(512), 0, stream,
                     x, Wih0, Whh0, bih0, bhh0, Wih1, Whh1, bih1, bhh1, ws, R - 1);
  hipLaunchKernelGGL(cls_k, dim3(512), dim3(128), 0, stream,
                     ws, W1, b1, W2, b2, W3, b3, (float*)d_out);
}